// Round 7
// baseline (496.499 us; speedup 1.0000x reference)
//
#include <hip/hip_runtime.h>

#define NN 100000
#define EE 1000000
#define FF 128
#define HH 64
#define GG 128
#define NB 391   // scan blocks: 391*256 = 100096 >= NN

__device__ inline unsigned short f2bf(float f) {
    unsigned u = __float_as_uint(f);
    u += 0x7fffu + ((u >> 16) & 1u);
    return (unsigned short)(u >> 16);
}

// ---------- CSR build (padded: slots = align4(deg+1); self at start, pads -> zero row NN) ----------
__global__ void k_hist(const int* __restrict__ ei, int* __restrict__ cnt) {
    int e = blockIdx.x * 256 + threadIdx.x;
    if (e < EE) atomicAdd(&cnt[ei[EE + e]], 1);
}

__global__ void k_scan1(const int* __restrict__ cnt, int* __restrict__ part,
                        unsigned short* __restrict__ B) {
    if (blockIdx.x == 0 && threadIdx.x < HH) B[(size_t)NN * HH + threadIdx.x] = 0;  // zero row
    int i = blockIdx.x * 256 + threadIdx.x;
    int v = (i < NN) ? ((cnt[i] + 4) & ~3) : 0;
    for (int o = 1; o < 64; o <<= 1) v += __shfl_xor(v, o);
    __shared__ int ws[4];
    if ((threadIdx.x & 63) == 0) ws[threadIdx.x >> 6] = v;
    __syncthreads();
    if (threadIdx.x == 0) part[blockIdx.x] = ws[0] + ws[1] + ws[2] + ws[3];
}

__global__ void k_scan2(int* __restrict__ part) {   // exclusive scan, 1 block
    __shared__ int buf[512];
    int t = threadIdx.x;
    int v = (t < NB) ? part[t] : 0;
    buf[t] = v; __syncthreads();
    for (int o = 1; o < 512; o <<= 1) {
        int u = (t >= o) ? buf[t - o] : 0;
        __syncthreads();
        buf[t] += u;
        __syncthreads();
    }
    if (t < NB) part[t] = buf[t] - v;
}

__global__ void k_scan3(const int* __restrict__ cnt, const int* __restrict__ part,
                        int* __restrict__ row_ptr, int* __restrict__ cursor,
                        int* __restrict__ srcs, float* __restrict__ dis) {
    int i = blockIdx.x * 256 + threadIdx.x;
    int c = (i < NN) ? cnt[i] : 0;
    int slots = (c + 4) & ~3;
    int v = (i < NN) ? slots : 0;
    int lane = threadIdx.x & 63, w = threadIdx.x >> 6;
    int incl = v;
    for (int o = 1; o < 64; o <<= 1) { int u = __shfl_up(incl, o); if (lane >= o) incl += u; }
    __shared__ int ws[4];
    if (lane == 63) ws[w] = incl;
    __syncthreads();
    int woff = 0;
    for (int k = 0; k < w; ++k) woff += ws[k];
    int excl = incl - v + woff + part[blockIdx.x];
    if (i < NN) {
        row_ptr[i] = excl;
        cursor[i]  = excl + 1;            // edges fill after the self slot
        srcs[excl] = i;                   // self-loop as a regular slot
        for (int t = c + 1; t < slots; ++t) srcs[excl + t] = NN;   // pads -> zero row
        dis[i] = rsqrtf((float)(c + 1));
        if (i == NN - 1) row_ptr[NN] = excl + slots;
    }
}

__global__ void k_place(const int* __restrict__ ei, int* __restrict__ cursor,
                        int* __restrict__ srcs) {
    int e = blockIdx.x * 256 + threadIdx.x;
    if (e < EE) {
        int d = ei[EE + e];
        int p = atomicAdd(&cursor[d], 1);
        srcs[p] = ei[e];
    }
}

// ---------- dense: Y[N,64] = bf16( (X[N,K] @ W[K,64]) * dis[row] ) ----------
template<int K>
__global__ __launch_bounds__(256) void
k_matmul_b(const float* __restrict__ X, const float* __restrict__ W,
           const float* __restrict__ dis, unsigned short* __restrict__ Y) {
    __shared__ float Wl[K * HH];
    for (int i = threadIdx.x; i < K * HH; i += 256) Wl[i] = W[i];
    __syncthreads();
    const int lane = threadIdx.x & 63;
    const int wv   = threadIdx.x >> 6;
    const int c4   = (lane & 15) * 4;
    const int rsg  = lane >> 4;
    const int r0   = blockIdx.x * 64 + wv * 16 + rsg * 4;

    const float* xr0; const float* xr1; const float* xr2; const float* xr3;
    {
        int a = r0,     b_ = r0 + 1, c = r0 + 2, d = r0 + 3;
        if (a > NN - 1) a = NN - 1;
        if (b_ > NN - 1) b_ = NN - 1;
        if (c > NN - 1) c = NN - 1;
        if (d > NN - 1) d = NN - 1;
        xr0 = X + (size_t)a * K; xr1 = X + (size_t)b_ * K;
        xr2 = X + (size_t)c * K; xr3 = X + (size_t)d * K;
    }
    float4 acc0 = {0,0,0,0}, acc1 = {0,0,0,0}, acc2 = {0,0,0,0}, acc3 = {0,0,0,0};

#pragma unroll 8
    for (int k4 = 0; k4 < K / 4; ++k4) {
        const float4 x0 = *(const float4*)(xr0 + k4 * 4);
        const float4 x1 = *(const float4*)(xr1 + k4 * 4);
        const float4 x2 = *(const float4*)(xr2 + k4 * 4);
        const float4 x3 = *(const float4*)(xr3 + k4 * 4);
        const float4 w0 = *(const float4*)&Wl[(k4 * 4 + 0) * HH + c4];
        const float4 w1 = *(const float4*)&Wl[(k4 * 4 + 1) * HH + c4];
        const float4 w2 = *(const float4*)&Wl[(k4 * 4 + 2) * HH + c4];
        const float4 w3 = *(const float4*)&Wl[(k4 * 4 + 3) * HH + c4];
#define FMA4(A, XS) \
        A.x = fmaf(XS.x, w0.x, A.x); A.y = fmaf(XS.x, w0.y, A.y); \
        A.z = fmaf(XS.x, w0.z, A.z); A.w = fmaf(XS.x, w0.w, A.w); \
        A.x = fmaf(XS.y, w1.x, A.x); A.y = fmaf(XS.y, w1.y, A.y); \
        A.z = fmaf(XS.y, w1.z, A.z); A.w = fmaf(XS.y, w1.w, A.w); \
        A.x = fmaf(XS.z, w2.x, A.x); A.y = fmaf(XS.z, w2.y, A.y); \
        A.z = fmaf(XS.z, w2.z, A.z); A.w = fmaf(XS.z, w2.w, A.w); \
        A.x = fmaf(XS.w, w3.x, A.x); A.y = fmaf(XS.w, w3.y, A.y); \
        A.z = fmaf(XS.w, w3.z, A.z); A.w = fmaf(XS.w, w3.w, A.w);
        FMA4(acc0, x0) FMA4(acc1, x1) FMA4(acc2, x2) FMA4(acc3, x3)
#undef FMA4
    }
#define STORE(I, A) { \
        const int r = r0 + I; \
        if (r < NN) { \
            const float d = dis[r]; \
            ushort4 o; \
            o.x = f2bf(A.x * d); o.y = f2bf(A.y * d); \
            o.z = f2bf(A.z * d); o.w = f2bf(A.w * d); \
            *(ushort4*)(Y + (size_t)r * HH + c4) = o; \
        } }
    STORE(0, acc0) STORE(1, acc1) STORE(2, acc2) STORE(3, acc3)
#undef STORE
}

// ---------- gather conv ----------
// 16-lane group per node (4 nodes/wave). Indices staged in LDS (lgkmcnt) so
// address formation never drains vmcnt. ALL of a node's gathers (up to 8
// batches x 4 rows) issue before any consume -> one random latency per node.
// Pads hit zero row NN; self-loop is slot 0. Rare deg>31: guarded tail.
#define AW(w) __uint_as_float((w) << 16)
#define AH(w) __uint_as_float((w) & 0xffff0000u)
template<bool POOL>
__global__ __launch_bounds__(256) void
k_gconv(const int* __restrict__ row_ptr, const int* __restrict__ srcs,
        const float* __restrict__ dis, const unsigned short* __restrict__ Hs,
        const float* __restrict__ b, float* __restrict__ Out,
        const int* __restrict__ batch, float* __restrict__ g) {
    __shared__ int L[16 * 32];
    const int grp  = threadIdx.x >> 4;      // 0..15: node within block
    const int li   = threadIdx.x & 15;      // col quad
    const int node = blockIdx.x * 16 + grp;
    const int p0   = row_ptr[node];
    const int pend = row_ptr[node + 1];
    const int slots = pend - p0;
    const int nbc  = (slots >> 2) < 8 ? (slots >> 2) : 8;
    int* Lg = L + grp * 32;
    for (int q = li; q < 32; q += 16)
        if (q < slots) Lg[q] = srcs[p0 + q];
    __syncthreads();

    float4 acc = {0.f, 0.f, 0.f, 0.f};
    uint2 r00,r01,r02,r03,r10,r11,r12,r13,r20,r21,r22,r23,r30,r31,r32,r33,
          r40,r41,r42,r43,r50,r51,r52,r53,r60,r61,r62,r63,r70,r71,r72,r73;
#define ISSUE(K,R0,R1,R2,R3) if (K < nbc) { \
    const size_t i0=Lg[4*K+0], i1=Lg[4*K+1], i2=Lg[4*K+2], i3=Lg[4*K+3]; \
    R0 = *(const uint2*)(Hs + i0*HH + li*4); \
    R1 = *(const uint2*)(Hs + i1*HH + li*4); \
    R2 = *(const uint2*)(Hs + i2*HH + li*4); \
    R3 = *(const uint2*)(Hs + i3*HH + li*4); }
    ISSUE(0,r00,r01,r02,r03) ISSUE(1,r10,r11,r12,r13)
    ISSUE(2,r20,r21,r22,r23) ISSUE(3,r30,r31,r32,r33)
    ISSUE(4,r40,r41,r42,r43) ISSUE(5,r50,r51,r52,r53)
    ISSUE(6,r60,r61,r62,r63) ISSUE(7,r70,r71,r72,r73)
#undef ISSUE
#define CONS(K,R0,R1,R2,R3) if (K < nbc) { \
    acc.x += AW(R0.x) + AW(R1.x) + AW(R2.x) + AW(R3.x); \
    acc.y += AH(R0.x) + AH(R1.x) + AH(R2.x) + AH(R3.x); \
    acc.z += AW(R0.y) + AW(R1.y) + AW(R2.y) + AW(R3.y); \
    acc.w += AH(R0.y) + AH(R1.y) + AH(R2.y) + AH(R3.y); }
    CONS(0,r00,r01,r02,r03) CONS(1,r10,r11,r12,r13)
    CONS(2,r20,r21,r22,r23) CONS(3,r30,r31,r32,r33)
    CONS(4,r40,r41,r42,r43) CONS(5,r50,r51,r52,r53)
    CONS(6,r60,r61,r62,r63) CONS(7,r70,r71,r72,r73)
#undef CONS
    // rare tail (slots > 32)
    for (int q = p0 + 32; q < pend; ++q) {
        const size_t s = srcs[q];
        uint2 v = *(const uint2*)(Hs + s * HH + li * 4);
        acc.x += AW(v.x); acc.y += AH(v.x); acc.z += AW(v.y); acc.w += AH(v.y);
    }
    const float dd = dis[node];
    const float4 bv = *(const float4*)(b + li * 4);
    float4 v;
    v.x = fmaxf(fmaf(acc.x, dd, bv.x), 0.f);
    v.y = fmaxf(fmaf(acc.y, dd, bv.y), 0.f);
    v.z = fmaxf(fmaf(acc.z, dd, bv.z), 0.f);
    v.w = fmaxf(fmaf(acc.w, dd, bv.w), 0.f);
    if (POOL) {
        float* gp = g + (size_t)batch[node] * HH + li * 4;
        unsafeAtomicAdd(gp + 0, v.x); unsafeAtomicAdd(gp + 1, v.y);
        unsafeAtomicAdd(gp + 2, v.z); unsafeAtomicAdd(gp + 3, v.w);
    } else {
        *(float4*)(Out + (size_t)node * HH + li * 4) = v;
    }
}

// ---------- head ----------
__global__ void k_head1(const float* __restrict__ g, const float* __restrict__ W,
                        const float* __restrict__ b, float* __restrict__ g2) {
    const int idx = blockIdx.x * 256 + threadIdx.x;
    const int row = idx >> 6;
    const int col = idx & 63;
    const float* gr = g + (size_t)row * HH;
    float acc = b[col];
#pragma unroll
    for (int k = 0; k < HH; ++k) acc = fmaf(gr[k], W[k * HH + col], acc);
    g2[idx] = acc > 0.0f ? acc : 0.0f;
}

__global__ void k_head2(const float* __restrict__ g2, const float* __restrict__ W,
                        const float* __restrict__ b, float* __restrict__ out) {
    const int r = threadIdx.x;
    if (r >= GG) return;
    const float* gr = g2 + (size_t)r * HH;
    float acc = 0.0f;
#pragma unroll
    for (int k = 0; k < HH; ++k) acc = fmaf(gr[k], W[k], acc);
    out[r] = acc + b[0];
}

extern "C" void kernel_launch(void* const* d_in, const int* in_sizes, int n_in,
                              void* d_out, int out_size, void* d_ws, size_t ws_size,
                              hipStream_t stream) {
    const float* x   = (const float*)d_in[0];
    const int*   ei  = (const int*)d_in[1];
    const int*   bat = (const int*)d_in[2];
    const float* W1  = (const float*)d_in[3];
    const float* b1  = (const float*)d_in[4];
    const float* W2  = (const float*)d_in[5];
    const float* b2  = (const float*)d_in[6];
    const float* Wl1 = (const float*)d_in[7];
    const float* bl1 = (const float*)d_in[8];
    const float* Wl2 = (const float*)d_in[9];
    const float* bl2 = (const float*)d_in[10];
    float* out = (float*)d_out;

    char* w = (char*)d_ws;
    float* dis     = (float*)(w);                    // 400,128 B
    int*   cnt     = (int*)  (w + 400128);           // 400,128 B
    int*   row_ptr = (int*)  (w + 800256);           // 400,384 B (N+1)
    int*   cursor  = (int*)  (w + 1200640);          // 400,128 B
    int*   part    = (int*)  (w + 1600768);          // 2,048 B
    int*   srcs    = (int*)  (w + 1602816);          // 6,000,000 B (padded CSR <= 1.4M ints)
    unsigned short* B = (unsigned short*)(w + 7602816); // (N+1)*64 bf16 = 12,800,128 B
    float* A       = (float*)(w + 20403200);         // 25,600,000 B
    float* g       = (float*)(w + 46003200);         // 32 KB + head scratch
    float* g2      = g + GG * HH;

    // ---- CSR build (once; reused by both convs) ----
    hipMemsetAsync(cnt, 0, (size_t)NN * sizeof(int), stream);
    k_hist <<<(EE + 255) / 256, 256, 0, stream>>>(ei, cnt);
    k_scan1<<<NB, 256, 0, stream>>>(cnt, part, B);
    k_scan2<<<1, 512, 0, stream>>>(part);
    k_scan3<<<NB, 256, 0, stream>>>(cnt, part, row_ptr, cursor, srcs, dis);
    k_place<<<(EE + 255) / 256, 256, 0, stream>>>(ei, cursor, srcs);

    // ---- conv1 ----
    k_matmul_b<FF><<<(NN + 63) / 64, 256, 0, stream>>>(x, W1, dis, B);
    k_gconv<false><<<NN / 16, 256, 0, stream>>>(row_ptr, srcs, dis, B, b1, A, nullptr, nullptr);

    // ---- conv2 (pool fused) ----
    k_matmul_b<HH><<<(NN + 63) / 64, 256, 0, stream>>>(A, W2, dis, B);
    hipMemsetAsync(g, 0, (size_t)GG * HH * sizeof(float), stream);
    k_gconv<true><<<NN / 16, 256, 0, stream>>>(row_ptr, srcs, dis, B, b2, nullptr, bat, g);

    // ---- head ----
    k_head1<<<(GG * HH) / 256, 256, 0, stream>>>(g, Wl1, bl1, g2);
    k_head2<<<1, 128, 0, stream>>>(g2, Wl2, bl2, out);
}